// Round 1
// baseline (905.186 us; speedup 1.0000x reference)
//
#include <hip/hip_runtime.h>
#include <cmath>
#include <cstdint>
#include <cstddef>

typedef _Float16 f16;
typedef _Float16 f16x8 __attribute__((ext_vector_type(8)));
typedef float f32x4 __attribute__((ext_vector_type(4)));

// ---- problem constants ----
#define BATCH 8
#define CIN   512
#define COUT  512
#define S0    64      // input spatial
#define S1    66      // conv output spatial (pad 2, k=3)
#define PADH  68      // padded input spatial for conv
#define P_TOT (S1*S1) // 4356 spatial positions per image
#define MID   138     // mid (upsampled+filtered) spatial
#define OUTS  64      // final output spatial

struct FirParams { float fu[12]; float fd[12]; };

// ---------------------------------------------------------------- helpers
__device__ __forceinline__ void async16(const char* g, char* l) {
  __builtin_amdgcn_global_load_lds((const __attribute__((address_space(1))) void*)g,
                                   (__attribute__((address_space(3))) void*)l, 16, 0, 0);
}

// ---------------------------------------------------------------- K1: styles = w @ (aw^T/sqrt(512)) + ab
__global__ __launch_bounds__(256) void k_styles(const float* __restrict__ w,
                                                const float* __restrict__ aw,
                                                const float* __restrict__ ab,
                                                float* __restrict__ styles) {
  int id = blockIdx.x*256 + threadIdx.x;        // 0..4095
  int b = id >> 9, i = id & 511;
  const float* wr = w + b*512;
  const float* ar = aw + (size_t)i*512;
  float acc = 0.f;
  for (int k = 0; k < 512; ++k) acc += wr[k]*ar[k];
  styles[id] = acc*0.044194173824159216f + ab[i];  // 1/sqrt(512)
}

// ---------------------------------------------------------------- K2: s_n = styles * rsqrt(mean(styles^2))
__global__ __launch_bounds__(256) void k_snorm(const float* __restrict__ styles,
                                               float* __restrict__ s_n) {
  __shared__ float red[256];
  int tid = threadIdx.x;
  float acc = 0.f;
  for (int i = tid; i < 4096; i += 256) { float v = styles[i]; acc += v*v; }
  red[tid] = acc; __syncthreads();
  for (int s = 128; s > 0; s >>= 1) {
    if (tid < s) red[tid] += red[tid+s];
    __syncthreads();
  }
  float scale = 1.0f/sqrtf(red[0]*(1.0f/4096.0f));
  for (int i = tid; i < 4096; i += 256) s_n[i] = styles[i]*scale;
}

// ---------------------------------------------------------------- K3: g[O][I] = sum_tap wgt^2
__global__ __launch_bounds__(256) void k_g(const float* __restrict__ cw,
                                           float* __restrict__ g) {
  int id = blockIdx.x*256 + threadIdx.x;  // 0..262143
  if (id >= 512*512) return;
  const float* p = cw + (size_t)id*9;
  float acc = 0.f;
  #pragma unroll
  for (int t = 0; t < 9; ++t) acc += p[t]*p[t];
  g[id] = acc;
}

// ---------------------------------------------------------------- K4: scale_o[b][O] = wn[O]*demod[b][O]
__global__ __launch_bounds__(64) void k_scale(const float* __restrict__ g,
                                              const float* __restrict__ s_n,
                                              float* __restrict__ sco) {
  int blk = blockIdx.x;              // b*512 + O
  int b = blk >> 9, O = blk & 511;
  int lane = threadIdx.x;
  const float* gr = g + (size_t)O*512;
  const float* sr = s_n + b*512;
  float a1 = 0.f, a2 = 0.f;
  for (int I = lane; I < 512; I += 64) {
    float gg = gr[I], ss = sr[I];
    a1 += gg*ss*ss; a2 += gg;
  }
  for (int off = 32; off; off >>= 1) {
    a1 += __shfl_down(a1, off);
    a2 += __shfl_down(a2, off);
  }
  if (lane == 0) {
    float wn2 = 4608.f / a2;                              // 1/mean(wgt^2)
    sco[blk] = sqrtf(wn2) / sqrtf(wn2*a1 + 1e-8f);        // wn * rsqrt(sum wb^2 + eps)
  }
}

// ---------------------------------------------------------------- K5: Wp[O][tap][I] = f16(cw[O][I][tap])
__global__ __launch_bounds__(128) void k_wprep(const float* __restrict__ cw,
                                               f16* __restrict__ Wp) {
  int blk = blockIdx.x;              // O*9 + tap
  int O = blk / 9, t = blk - O*9;
  f16* op = Wp + ((size_t)O*9 + t)*512;
  const float* ip = cw + (size_t)O*512*9 + t;
  for (int I = threadIdx.x; I < 512; I += 128)
    op[I] = (f16)ip[(size_t)I*9];
}

// ---------------------------------------------------------------- K6: Xm[b][ih+2][iw+2][I] = f16(x[b][I][ih][iw]*s_n[b][I])
__global__ __launch_bounds__(256) void k_xmod(const float* __restrict__ x,
                                              const float* __restrict__ s_n,
                                              f16* __restrict__ Xm) {
  __shared__ float tile[128][65];
  int blk = blockIdx.x;              // b*256 + ih*4 + ic
  int ic = blk & 3, ih = (blk >> 2) & 63, b = blk >> 8;
  int I0 = ic*128;
  const float* xp = x + (((size_t)b*512 + I0)*64 + ih)*64;
  for (int idx = threadIdx.x; idx < 128*64; idx += 256) {
    int Il = idx >> 6, iw = idx & 63;
    tile[Il][iw] = xp[(size_t)Il*4096 + iw] * s_n[b*512 + I0 + Il];
  }
  __syncthreads();
  f16* op = Xm + (((size_t)b*PADH + ih + 2)*PADH + 2)*512 + I0;
  for (int idx = threadIdx.x; idx < 64*128; idx += 256) {
    int iw = idx >> 7, Il = idx & 127;
    op[(size_t)iw*512 + Il] = (f16)tile[Il][iw];
  }
}

// ---------------------------------------------------------------- K7: modulated conv as 9-tap implicit GEMM
// C[O (128 rows)][p (128 cols)] per block; K = 9 taps x 512 I, BK=64.
// LDS 16B chunks XOR-swizzled by row%8 to dodge stride-128B bank conflicts
// while honoring global_load_lds's (uniform base + lane*16) LDS dest.
__global__ __launch_bounds__(256) void k_conv(const f16* __restrict__ Wp,
                                              const f16* __restrict__ Xm,
                                              const float* __restrict__ sco,
                                              const float* __restrict__ bias,
                                              f16* __restrict__ y1) {
  __shared__ f16x8 As[1024];   // 128 rows x 8 chunks (16KB)
  __shared__ f16x8 Bs[1024];
  const int tid = threadIdx.x, lane = tid & 63, wave = tid >> 6;
  const int Ot = blockIdx.x*128, pt0 = blockIdx.y*128, b = blockIdx.z;

  // staging: wave stages rows [wave*32, wave*32+32) of both tiles; 4 issues of 8 rows
  const int srow = wave*32 + (lane >> 3);
  const int cglob = (lane & 7) ^ (lane >> 3);     // global chunk feeding physical chunk lane&7
  const char* aP[4]; const char* bP[4];
  #pragma unroll
  for (int q = 0; q < 4; ++q) {
    int arow = Ot + srow + q*8;
    aP[q] = (const char*)Wp + (size_t)arow*9216 + cglob*16;
    int p = pt0 + srow + q*8; if (p > P_TOT-1) p = P_TOT-1;   // clamp tail tile
    int oh = p/66, ow = p - oh*66;
    size_t pix = ((size_t)b*PADH + oh)*PADH + ow;
    bP[q] = (const char*)Xm + pix*1024 + cglob*16;
  }
  char* aL = (char*)As + wave*32*128;
  char* bL = (char*)Bs + wave*32*128;

  f32x4 acc[4][4] = {};
  const int wO = (wave & 1)*64, wPq = (wave >> 1)*64;
  const int m = lane & 15, quad = lane >> 4, mx = m & 7;

  for (int tap = 0; tap < 9; ++tap) {
    const int kh = tap/3, kw = tap - kh*3;
    const uint32_t bTap = (uint32_t)(kh*PADH + kw)*1024u;
    const uint32_t aTap = (uint32_t)tap*1024u;
    for (uint32_t I0b = 0; I0b < 1024; I0b += 128) {   // bytes of I offset (BK=64 f16)
      __syncthreads();
      #pragma unroll
      for (int q = 0; q < 4; ++q) async16(aP[q] + aTap + I0b, aL + q*1024);
      #pragma unroll
      for (int q = 0; q < 4; ++q) async16(bP[q] + bTap + I0b, bL + q*1024);
      __syncthreads();
      #pragma unroll
      for (int ks = 0; ks < 2; ++ks) {
        f16x8 af[4], bf[4];
        #pragma unroll
        for (int i = 0; i < 4; ++i)
          af[i] = As[(wO + i*16 + m)*8 + ((ks*4 + quad) ^ mx)];
        #pragma unroll
        for (int j = 0; j < 4; ++j)
          bf[j] = Bs[(wPq + j*16 + m)*8 + ((ks*4 + quad) ^ mx)];
        #pragma unroll
        for (int i = 0; i < 4; ++i)
          #pragma unroll
          for (int j = 0; j < 4; ++j)
            acc[i][j] = __builtin_amdgcn_mfma_f32_16x16x32_f16(af[i], bf[j], acc[i][j], 0, 0, 0);
      }
    }
  }

  // epilogue: y1[b][O][p] = f16(acc*scale_o + bias)
  #pragma unroll
  for (int i = 0; i < 4; ++i) {
    #pragma unroll
    for (int r = 0; r < 4; ++r) {
      int orow = Ot + wO + i*16 + quad*4 + r;
      float sc = sco[b*COUT + orow];
      float bb = bias[orow];
      f16* yrow = y1 + ((size_t)(b*COUT + orow))*P_TOT;
      #pragma unroll
      for (int j = 0; j < 4; ++j) {
        int p = pt0 + wPq + j*16 + m;
        if (p < P_TOT) yrow[p] = (f16)(acc[i][j][r]*sc + bb);
      }
    }
  }
}

// ---------------------------------------------------------------- K8: fused up-FIR -> lrelu/clamp -> down-FIR per channel
// Polyphase: mid index parity selects even/odd taps of fu (6 taps each), x4 up gain.
__global__ __launch_bounds__(256) void k_fir(const f16* __restrict__ y1,
                                             float* __restrict__ out,
                                             FirParams fp) {
  __shared__ float H[MID][64];   // horizontal-downsampled rows (35.3KB)
  __shared__ float VU[8][80];    // vertical-up chunk, col range [-4,69] at +4
  __shared__ float Q[8][140];    // activated mid rows
  const int tid = threadIdx.x;
  const f16* Y = y1 + (size_t)blockIdx.x * P_TOT;
  float* O = out + (size_t)blockIdx.x * (OUTS*OUTS);

  for (int m0 = 0; m0 < MID; m0 += 8) {
    const int nr = (MID - m0) < 8 ? (MID - m0) : 8;
    // vertical polyphase upsample (+gain 4)
    for (int idx = tid; idx < nr*74; idx += 256) {
      int lr = idx/74, colx = idx - lr*74;
      int col = colx - 4, mm = m0 + lr;
      float acc = 0.f;
      if (col >= 0 && col < 66) {
        if (mm & 1) {
          int base = (mm + 1) >> 1;
          #pragma unroll
          for (int a = 0; a < 6; ++a) { int r = base - a; if ((unsigned)r < 66u) acc += fp.fu[2*a+1]*(float)Y[r*66 + col]; }
        } else {
          int base = (mm >> 1) + 1;
          #pragma unroll
          for (int a = 0; a < 6; ++a) { int r = base - a; if ((unsigned)r < 66u) acc += fp.fu[2*a]*(float)Y[r*66 + col]; }
        }
        acc *= 4.f;
      }
      VU[lr][colx] = acc;
    }
    __syncthreads();
    // horizontal polyphase upsample + activation
    for (int idx = tid; idx < nr*138; idx += 256) {
      int lr = idx/138, mc = idx - lr*138;
      float acc = 0.f;
      if (mc & 1) {
        int base = (mc + 1) >> 1;
        #pragma unroll
        for (int t = 0; t < 6; ++t) acc += fp.fu[2*t+1]*VU[lr][base - t + 4];
      } else {
        int base = (mc >> 1) + 1;
        #pragma unroll
        for (int t = 0; t < 6; ++t) acc += fp.fu[2*t]*VU[lr][base - t + 4];
      }
      float v = (acc >= 0.f ? acc : 0.2f*acc) * 1.4142135623730951f;
      Q[lr][mc] = fminf(fmaxf(v, -256.f), 256.f);
    }
    __syncthreads();
    // horizontal down (stride 2)
    for (int idx = tid; idx < nr*64; idx += 256) {
      int lr = idx >> 6, tc = idx & 63;
      float acc = 0.f;
      #pragma unroll
      for (int j = 0; j < 12; ++j) acc += fp.fd[j]*Q[lr][2*tc + 11 - j];
      H[m0 + lr][tc] = acc;
    }
    __syncthreads();
  }
  // vertical down (stride 2)
  for (int idx = tid; idx < OUTS*OUTS; idx += 256) {
    int tr = idx >> 6, tc = idx & 63;
    float acc = 0.f;
    #pragma unroll
    for (int j = 0; j < 12; ++j) acc += fp.fd[j]*H[2*tr + 11 - j][tc];
    O[idx] = acc;
  }
}

// ---------------------------------------------------------------- host: Kaiser lowpass design (double precision)
static double bessel_i0(double x) {
  double t = 0.25*x*x, sum = 1.0, term = 1.0;
  for (int k = 1; k < 64; ++k) {
    term *= t/((double)k*(double)k);
    sum += term;
    if (term < 1e-18*sum) break;
  }
  return sum;
}

static void design_lp(int numtaps, double cutoff, double width, double fs, float* out) {
  const double PI = 3.14159265358979323846;
  double a = 2.285*(numtaps - 1)*PI*(width/(0.5*fs)) + 7.95;
  double beta;
  if (a > 50.0)      beta = 0.1102*(a - 8.7);
  else if (a > 21.0) beta = 0.5842*pow(a - 21.0, 0.4) + 0.07886*(a - 21.0);
  else               beta = 0.0;
  double c = cutoff/(fs*0.5);
  double alpha = (numtaps - 1)*0.5;
  double i0b = bessel_i0(beta);
  double h[16], s = 0.0;
  for (int n = 0; n < numtaps; ++n) {
    double mm = n - alpha;
    double x = c*mm;
    double snc = (x == 0.0) ? 1.0 : sin(PI*x)/(PI*x);
    double r = mm/alpha;
    double kais = bessel_i0(beta*sqrt(fmax(0.0, 1.0 - r*r)))/i0b;
    h[n] = c*snc*kais; s += h[n];
  }
  for (int n = 0; n < numtaps; ++n) out[n] = (float)(h[n]/s);
}

// ---------------------------------------------------------------- launcher
extern "C" void kernel_launch(void* const* d_in, const int* in_sizes, int n_in,
                              void* d_out, int out_size, void* d_ws, size_t ws_size,
                              hipStream_t stream) {
  const float* x  = (const float*)d_in[0];
  const float* w  = (const float*)d_in[1];
  const float* aw = (const float*)d_in[2];
  const float* ab = (const float*)d_in[3];
  const float* cw = (const float*)d_in[4];
  const float* cb = (const float*)d_in[5];
  float* out = (float*)d_out;

  char* ws = (char*)d_ws;
  size_t off = 0;
  auto alloc = [&](size_t bytes) -> char* {
    char* p = ws + off;
    off = (off + bytes + 255) & ~(size_t)255;
    return p;
  };
  float* styles = (float*)alloc(4096*4);
  float* s_n    = (float*)alloc(4096*4);
  float* g      = (float*)alloc((size_t)512*512*4);
  float* sco    = (float*)alloc(4096*4);
  f16*   Wp     = (f16*)alloc((size_t)512*9*512*2);
  const size_t XM_BYTES = (size_t)BATCH*PADH*PADH*512*2;
  f16*   Xm     = (f16*)alloc(XM_BYTES);
  f16*   y1     = (f16*)alloc((size_t)BATCH*COUT*P_TOT*2);
  (void)in_sizes; (void)n_in; (void)out_size; (void)ws_size;

  FirParams fp;
  design_lp(12, 32.0, 32.0, 128.0, fp.fu);
  design_lp(12, 32.0, 32.0, 128.0, fp.fd);

  hipMemsetAsync(Xm, 0, XM_BYTES, stream);   // zero padding halo
  hipLaunchKernelGGL(k_styles, dim3(16),        dim3(256), 0, stream, w, aw, ab, styles);
  hipLaunchKernelGGL(k_snorm,  dim3(1),         dim3(256), 0, stream, styles, s_n);
  hipLaunchKernelGGL(k_g,      dim3(1024),      dim3(256), 0, stream, cw, g);
  hipLaunchKernelGGL(k_scale,  dim3(4096),      dim3(64),  0, stream, g, s_n, sco);
  hipLaunchKernelGGL(k_wprep,  dim3(4608),      dim3(128), 0, stream, cw, Wp);
  hipLaunchKernelGGL(k_xmod,   dim3(2048),      dim3(256), 0, stream, x, s_n, Xm);
  hipLaunchKernelGGL(k_conv,   dim3(4, 35, 8),  dim3(256), 0, stream, Wp, Xm, sco, cb, y1);
  hipLaunchKernelGGL(k_fir,    dim3(4096),      dim3(256), 0, stream, y1, out, fp);
}

// Round 2
// 514.776 us; speedup vs baseline: 1.7584x; 1.7584x over previous
//
#include <hip/hip_runtime.h>
#include <cmath>
#include <cstdint>
#include <cstddef>

typedef _Float16 f16;
typedef _Float16 f16x2 __attribute__((ext_vector_type(2)));
typedef _Float16 f16x8 __attribute__((ext_vector_type(8)));
typedef float f32x4 __attribute__((ext_vector_type(4)));

// ---- problem constants ----
#define BATCH 8
#define CIN   512
#define COUT  512
#define S0    64      // input spatial
#define S1    66      // conv output spatial (pad 2, k=3)
#define PADH  68      // padded input spatial for conv
#define P_TOT (S1*S1) // 4356 spatial positions per image
#define MID   138     // mid (upsampled+filtered) spatial
#define OUTS  64      // final output spatial

struct FirParams { float fu[12]; float fd[12]; };

// ---------------------------------------------------------------- helpers
__device__ __forceinline__ void async16(const char* g, char* l) {
  __builtin_amdgcn_global_load_lds((const __attribute__((address_space(1))) void*)g,
                                   (__attribute__((address_space(3))) void*)l, 16, 0, 0);
}

// ---------------------------------------------------------------- K1: styles = w @ (aw^T/sqrt(512)) + ab
__global__ __launch_bounds__(256) void k_styles(const float* __restrict__ w,
                                                const float* __restrict__ aw,
                                                const float* __restrict__ ab,
                                                float* __restrict__ styles) {
  int id = blockIdx.x*256 + threadIdx.x;        // 0..4095
  int b = id >> 9, i = id & 511;
  const float* wr = w + b*512;
  const float* ar = aw + (size_t)i*512;
  float acc = 0.f;
  for (int k = 0; k < 512; ++k) acc += wr[k]*ar[k];
  styles[id] = acc*0.044194173824159216f + ab[i];  // 1/sqrt(512)
}

// ---------------------------------------------------------------- K2: s_n = styles * rsqrt(mean(styles^2))
__global__ __launch_bounds__(256) void k_snorm(const float* __restrict__ styles,
                                               float* __restrict__ s_n) {
  __shared__ float red[256];
  int tid = threadIdx.x;
  float acc = 0.f;
  for (int i = tid; i < 4096; i += 256) { float v = styles[i]; acc += v*v; }
  red[tid] = acc; __syncthreads();
  for (int s = 128; s > 0; s >>= 1) {
    if (tid < s) red[tid] += red[tid+s];
    __syncthreads();
  }
  float scale = 1.0f/sqrtf(red[0]*(1.0f/4096.0f));
  for (int i = tid; i < 4096; i += 256) s_n[i] = styles[i]*scale;
}

// ---------------------------------------------------------------- K3: g[O][I] = sum_tap wgt^2
__global__ __launch_bounds__(256) void k_g(const float* __restrict__ cw,
                                           float* __restrict__ g) {
  int id = blockIdx.x*256 + threadIdx.x;  // 0..262143
  if (id >= 512*512) return;
  const float* p = cw + (size_t)id*9;
  float acc = 0.f;
  #pragma unroll
  for (int t = 0; t < 9; ++t) acc += p[t]*p[t];
  g[id] = acc;
}

// ---------------------------------------------------------------- K4: scale_o[b][O] = wn[O]*demod[b][O]
__global__ __launch_bounds__(64) void k_scale(const float* __restrict__ g,
                                              const float* __restrict__ s_n,
                                              float* __restrict__ sco) {
  int blk = blockIdx.x;              // b*512 + O
  int b = blk >> 9, O = blk & 511;
  int lane = threadIdx.x;
  const float* gr = g + (size_t)O*512;
  const float* sr = s_n + b*512;
  float a1 = 0.f, a2 = 0.f;
  for (int I = lane; I < 512; I += 64) {
    float gg = gr[I], ss = sr[I];
    a1 += gg*ss*ss; a2 += gg;
  }
  for (int off = 32; off; off >>= 1) {
    a1 += __shfl_down(a1, off);
    a2 += __shfl_down(a2, off);
  }
  if (lane == 0) {
    float wn2 = 4608.f / a2;                              // 1/mean(wgt^2)
    sco[blk] = sqrtf(wn2) / sqrtf(wn2*a1 + 1e-8f);        // wn * rsqrt(sum wb^2 + eps)
  }
}

// ---------------------------------------------------------------- K5: Wp[O][tap][I] = f16(cw[O][I][tap])
__global__ __launch_bounds__(128) void k_wprep(const float* __restrict__ cw,
                                               f16* __restrict__ Wp) {
  int blk = blockIdx.x;              // O*9 + tap
  int O = blk / 9, t = blk - O*9;
  f16* op = Wp + ((size_t)O*9 + t)*512;
  const float* ip = cw + (size_t)O*512*9 + t;
  for (int I = threadIdx.x; I < 512; I += 128)
    op[I] = (f16)ip[(size_t)I*9];
}

// ---------------------------------------------------------------- K6: Xm[b][ih+2][iw+2][I] = f16(x[b][I][ih][iw]*s_n[b][I])
__global__ __launch_bounds__(256) void k_xmod(const float* __restrict__ x,
                                              const float* __restrict__ s_n,
                                              f16* __restrict__ Xm) {
  __shared__ float tile[128][65];
  int blk = blockIdx.x;              // b*256 + ih*4 + ic
  int ic = blk & 3, ih = (blk >> 2) & 63, b = blk >> 8;
  int I0 = ic*128;
  const float* xp = x + (((size_t)b*512 + I0)*64 + ih)*64;
  for (int idx = threadIdx.x; idx < 128*64; idx += 256) {
    int Il = idx >> 6, iw = idx & 63;
    tile[Il][iw] = xp[(size_t)Il*4096 + iw] * s_n[b*512 + I0 + Il];
  }
  __syncthreads();
  f16* op = Xm + (((size_t)b*PADH + ih + 2)*PADH + 2)*512 + I0;
  for (int idx = threadIdx.x; idx < 64*128; idx += 256) {
    int iw = idx >> 7, Il = idx & 127;
    op[(size_t)iw*512 + Il] = (f16)tile[Il][iw];
  }
}

// ---------------------------------------------------------------- K7: modulated conv as 9-tap implicit GEMM
__global__ __launch_bounds__(256) void k_conv(const f16* __restrict__ Wp,
                                              const f16* __restrict__ Xm,
                                              const float* __restrict__ sco,
                                              const float* __restrict__ bias,
                                              f16* __restrict__ y1) {
  __shared__ f16x8 As[1024];   // 128 rows x 8 chunks (16KB)
  __shared__ f16x8 Bs[1024];
  const int tid = threadIdx.x, lane = tid & 63, wave = tid >> 6;
  const int Ot = blockIdx.x*128, pt0 = blockIdx.y*128, b = blockIdx.z;

  const int srow = wave*32 + (lane >> 3);
  const int cglob = (lane & 7) ^ (lane >> 3);     // global chunk feeding physical chunk lane&7
  const char* aP[4]; const char* bP[4];
  #pragma unroll
  for (int q = 0; q < 4; ++q) {
    int arow = Ot + srow + q*8;
    aP[q] = (const char*)Wp + (size_t)arow*9216 + cglob*16;
    int p = pt0 + srow + q*8; if (p > P_TOT-1) p = P_TOT-1;   // clamp tail tile
    int oh = p/66, ow = p - oh*66;
    size_t pix = ((size_t)b*PADH + oh)*PADH + ow;
    bP[q] = (const char*)Xm + pix*1024 + cglob*16;
  }
  char* aL = (char*)As + wave*32*128;
  char* bL = (char*)Bs + wave*32*128;

  f32x4 acc[4][4] = {};
  const int wO = (wave & 1)*64, wPq = (wave >> 1)*64;
  const int m = lane & 15, quad = lane >> 4, mx = m & 7;

  for (int tap = 0; tap < 9; ++tap) {
    const int kh = tap/3, kw = tap - kh*3;
    const uint32_t bTap = (uint32_t)(kh*PADH + kw)*1024u;
    const uint32_t aTap = (uint32_t)tap*1024u;
    for (uint32_t I0b = 0; I0b < 1024; I0b += 128) {   // bytes of I offset (BK=64 f16)
      __syncthreads();
      #pragma unroll
      for (int q = 0; q < 4; ++q) async16(aP[q] + aTap + I0b, aL + q*1024);
      #pragma unroll
      for (int q = 0; q < 4; ++q) async16(bP[q] + bTap + I0b, bL + q*1024);
      __syncthreads();
      #pragma unroll
      for (int ks = 0; ks < 2; ++ks) {
        f16x8 af[4], bf[4];
        #pragma unroll
        for (int i = 0; i < 4; ++i)
          af[i] = As[(wO + i*16 + m)*8 + ((ks*4 + quad) ^ mx)];
        #pragma unroll
        for (int j = 0; j < 4; ++j)
          bf[j] = Bs[(wPq + j*16 + m)*8 + ((ks*4 + quad) ^ mx)];
        #pragma unroll
        for (int i = 0; i < 4; ++i)
          #pragma unroll
          for (int j = 0; j < 4; ++j)
            acc[i][j] = __builtin_amdgcn_mfma_f32_16x16x32_f16(af[i], bf[j], acc[i][j], 0, 0, 0);
      }
    }
  }

  #pragma unroll
  for (int i = 0; i < 4; ++i) {
    #pragma unroll
    for (int r = 0; r < 4; ++r) {
      int orow = Ot + wO + i*16 + quad*4 + r;
      float sc = sco[b*COUT + orow];
      float bb = bias[orow];
      f16* yrow = y1 + ((size_t)(b*COUT + orow))*P_TOT;
      #pragma unroll
      for (int j = 0; j < 4; ++j) {
        int p = pt0 + wPq + j*16 + m;
        if (p < P_TOT) yrow[p] = (f16)(acc[i][j][r]*sc + bb);
      }
    }
  }
}

// ---------------------------------------------------------------- K8: fused up-FIR -> lrelu/clamp -> down-FIR per channel
// Rewritten: Y staged in padded LDS (no global re-reads, no bounds checks),
// parity-paired polyphase (no divergence, shared taps), tap-blocked down-FIRs,
// rolling 32-row H buffer with delayed Vdown emit concurrent with Hdown.
// fu passed pre-scaled by 2 (x2 per up stage = x4 total up gain).
#define YPITCH 76
#define QPITCH 142   // pitch chosen so the stride-8 Hdown read pattern is only 4-way
#define HPITCH 68
__global__ __launch_bounds__(256) void k_fir(const f16* __restrict__ y1,
                                             float* __restrict__ out,
                                             FirParams fp) {
  __shared__ float Yl[74*YPITCH];   // padded Y: rows/cols -4..69 (22496 B)
  __shared__ float VU[8*YPITCH];    // vertical-up chunk, padded cols 0..73 (2432 B)
  __shared__ float Qs[8*QPITCH];    // activated mid rows (4544 B)
  __shared__ float Hr[32*HPITCH];   // rolling horizontal-down rows (8704 B)
  const int tid = threadIdx.x;
  const f16* Y = y1 + (size_t)blockIdx.x * P_TOT;
  float* O = out + (size_t)blockIdx.x * (OUTS*OUTS);

  // stage Y into padded LDS (zero halo, then u32-vectorized load)
  for (int i = tid; i < 74*YPITCH/2; i += 256)
    *(float2*)&Yl[2*i] = make_float2(0.f, 0.f);
  __syncthreads();
  const f16x2* Y2 = (const f16x2*)Y;
  for (int i = tid; i < 66*33; i += 256) {
    int r = i/33, d = i - 33*r;
    f16x2 v = Y2[33*r + d];
    *(float2*)&Yl[(r+4)*YPITCH + 4 + 2*d] = make_float2((float)v.x, (float)v.y);
  }
  __syncthreads();

  for (int k = 0; k <= 18; ++k) {
    const int m0 = 8*k;
    const int nr = (k < 17) ? 8 : (k == 17 ? 2 : 0);

    // ---- phase 1: vertical polyphase up (pairs share source rows) ----
    if (k < 18) {
      int npair = nr >> 1;
      if (tid < npair*37) {
        int tp = tid/37, c2 = tid - 37*tp;
        int T = (m0 >> 1) + tp;          // mid rows 2T, 2T+1; sources rows T-4..T+1 (+4 pad)
        float e0=0.f,e1=0.f,o0=0.f,o1=0.f;
        #pragma unroll
        for (int a = 0; a < 6; ++a) {
          float2 v = *(const float2*)&Yl[(T+5-a)*YPITCH + 2*c2];
          e0 += fp.fu[2*a]*v.x;   e1 += fp.fu[2*a]*v.y;
          o0 += fp.fu[2*a+1]*v.x; o1 += fp.fu[2*a+1]*v.y;
        }
        *(float2*)&VU[(2*tp)*YPITCH   + 2*c2] = make_float2(e0, e1);
        *(float2*)&VU[(2*tp+1)*YPITCH + 2*c2] = make_float2(o0, o1);
      }
    }
    __syncthreads();

    // ---- phase 2: horizontal polyphase up + act (3 col-pairs/thread, 8 shared reads) ----
    if (k < 18) {
      if (tid < nr*23) {
        int lr = tid/23, ug = tid - 23*lr;
        int U0 = 3*ug;
        float r[8];
        #pragma unroll
        for (int d = 0; d < 8; ++d) r[d] = VU[lr*YPITCH + U0 + d];
        #pragma unroll
        for (int u = 0; u < 3; ++u) {
          float e=0.f, o=0.f;
          #pragma unroll
          for (int t = 0; t < 6; ++t) {
            float v = r[u+5-t];
            e += fp.fu[2*t]*v; o += fp.fu[2*t+1]*v;
          }
          e = (e >= 0.f ? e : 0.2f*e)*1.4142135623730951f;
          o = (o >= 0.f ? o : 0.2f*o)*1.4142135623730951f;
          e = fminf(fmaxf(e, -256.f), 256.f);
          o = fminf(fmaxf(o, -256.f), 256.f);
          *(float2*)&Qs[lr*QPITCH + 2*(U0+u)] = make_float2(e, o);
        }
      }
    }
    __syncthreads();

    // ---- phase 3: Hdown (waves 0-1) || delayed Vdown emit (waves 2-3) ----
    if (k < 18 && tid < 128) {
      int lr = tid >> 4, tg = tid & 15;
      if (lr < nr) {
        float q[18];
        #pragma unroll
        for (int d = 0; d < 18; ++d) q[d] = Qs[lr*QPITCH + 8*tg + d];
        float a0=0.f,a1=0.f,a2=0.f,a3=0.f;
        #pragma unroll
        for (int j = 0; j < 12; ++j) {
          float c = fp.fd[j];
          a0 += c*q[11-j]; a1 += c*q[13-j]; a2 += c*q[15-j]; a3 += c*q[17-j];
        }
        *(float4*)&Hr[((m0+lr)&31)*HPITCH + 4*tg] = make_float4(a0,a1,a2,a3);
      }
    }
    if (k >= 3 && tid >= 128) {
      int s = tid - 128;
      int pg = s >> 6, tc = s & 63;
      int tr0 = ((k-3) << 2) + 2*pg;    // emit rows tr0, tr0+1
      int br = 2*tr0;
      float h[14];
      #pragma unroll
      for (int d = 0; d < 14; ++d) h[d] = Hr[((br+d)&31)*HPITCH + tc];
      float a0=0.f, a1=0.f;
      #pragma unroll
      for (int j = 0; j < 12; ++j) {
        float c = fp.fd[j];
        a0 += c*h[11-j]; a1 += c*h[13-j];
      }
      O[tr0*64 + tc]     = a0;
      O[(tr0+1)*64 + tc] = a1;
    }
    __syncthreads();
  }
}

// ---------------------------------------------------------------- host: Kaiser lowpass design (double precision)
static double bessel_i0(double x) {
  double t = 0.25*x*x, sum = 1.0, term = 1.0;
  for (int k = 1; k < 64; ++k) {
    term *= t/((double)k*(double)k);
    sum += term;
    if (term < 1e-18*sum) break;
  }
  return sum;
}

static void design_lp(int numtaps, double cutoff, double width, double fs, float* out) {
  const double PI = 3.14159265358979323846;
  double a = 2.285*(numtaps - 1)*PI*(width/(0.5*fs)) + 7.95;
  double beta;
  if (a > 50.0)      beta = 0.1102*(a - 8.7);
  else if (a > 21.0) beta = 0.5842*pow(a - 21.0, 0.4) + 0.07886*(a - 21.0);
  else               beta = 0.0;
  double c = cutoff/(fs*0.5);
  double alpha = (numtaps - 1)*0.5;
  double i0b = bessel_i0(beta);
  double h[16], s = 0.0;
  for (int n = 0; n < numtaps; ++n) {
    double mm = n - alpha;
    double x = c*mm;
    double snc = (x == 0.0) ? 1.0 : sin(PI*x)/(PI*x);
    double r = mm/alpha;
    double kais = bessel_i0(beta*sqrt(fmax(0.0, 1.0 - r*r)))/i0b;
    h[n] = c*snc*kais; s += h[n];
  }
  for (int n = 0; n < numtaps; ++n) out[n] = (float)(h[n]/s);
}

// ---------------------------------------------------------------- launcher
extern "C" void kernel_launch(void* const* d_in, const int* in_sizes, int n_in,
                              void* d_out, int out_size, void* d_ws, size_t ws_size,
                              hipStream_t stream) {
  const float* x  = (const float*)d_in[0];
  const float* w  = (const float*)d_in[1];
  const float* aw = (const float*)d_in[2];
  const float* ab = (const float*)d_in[3];
  const float* cw = (const float*)d_in[4];
  const float* cb = (const float*)d_in[5];
  float* out = (float*)d_out;

  char* ws = (char*)d_ws;
  size_t off = 0;
  auto alloc = [&](size_t bytes) -> char* {
    char* p = ws + off;
    off = (off + bytes + 255) & ~(size_t)255;
    return p;
  };
  float* styles = (float*)alloc(4096*4);
  float* s_n    = (float*)alloc(4096*4);
  float* g      = (float*)alloc((size_t)512*512*4);
  float* sco    = (float*)alloc(4096*4);
  f16*   Wp     = (f16*)alloc((size_t)512*9*512*2);
  const size_t XM_BYTES = (size_t)BATCH*PADH*PADH*512*2;
  f16*   Xm     = (f16*)alloc(XM_BYTES);
  f16*   y1     = (f16*)alloc((size_t)BATCH*COUT*P_TOT*2);
  (void)in_sizes; (void)n_in; (void)out_size; (void)ws_size;

  FirParams fp;
  design_lp(12, 32.0, 32.0, 128.0, fp.fu);
  design_lp(12, 32.0, 32.0, 128.0, fp.fd);
  for (int i = 0; i < 12; ++i) fp.fu[i] *= 2.0f;   // x2 per up stage = x4 total up gain (exact)

  hipMemsetAsync(Xm, 0, XM_BYTES, stream);   // zero padding halo
  hipLaunchKernelGGL(k_styles, dim3(16),        dim3(256), 0, stream, w, aw, ab, styles);
  hipLaunchKernelGGL(k_snorm,  dim3(1),         dim3(256), 0, stream, styles, s_n);
  hipLaunchKernelGGL(k_g,      dim3(1024),      dim3(256), 0, stream, cw, g);
  hipLaunchKernelGGL(k_scale,  dim3(4096),      dim3(64),  0, stream, g, s_n, sco);
  hipLaunchKernelGGL(k_wprep,  dim3(4608),      dim3(128), 0, stream, cw, Wp);
  hipLaunchKernelGGL(k_xmod,   dim3(2048),      dim3(256), 0, stream, x, s_n, Xm);
  hipLaunchKernelGGL(k_conv,   dim3(4, 35, 8),  dim3(256), 0, stream, Wp, Xm, sco, cb, y1);
  hipLaunchKernelGGL(k_fir,    dim3(4096),      dim3(256), 0, stream, y1, out, fp);
}

// Round 3
// 497.710 us; speedup vs baseline: 1.8187x; 1.0343x over previous
//
#include <hip/hip_runtime.h>
#include <cmath>
#include <cstdint>
#include <cstddef>

typedef _Float16 f16;
typedef _Float16 f16x2 __attribute__((ext_vector_type(2)));
typedef _Float16 f16x8 __attribute__((ext_vector_type(8)));
typedef float f32x4 __attribute__((ext_vector_type(4)));

// ---- problem constants ----
#define BATCH 8
#define CIN   512
#define COUT  512
#define S0    64      // input spatial
#define S1    66      // conv output spatial (pad 2, k=3)
#define PADH  68      // padded input spatial for conv
#define P_TOT (S1*S1) // 4356 spatial positions per image
#define MID   138     // mid (upsampled+filtered) spatial
#define OUTS  64      // final output spatial

struct FirParams { float fu[12]; float fd[12]; };

// ---------------------------------------------------------------- helpers
__device__ __forceinline__ void async16(const char* g, char* l) {
  __builtin_amdgcn_global_load_lds((const __attribute__((address_space(1))) void*)g,
                                   (__attribute__((address_space(3))) void*)l, 16, 0, 0);
}

// ---------------------------------------------------------------- K1: styles = w @ (aw^T/sqrt(512)) + ab
// one wave per output element; coalesced aw reads + shuffle reduce
__global__ __launch_bounds__(256) void k_styles(const float* __restrict__ w,
                                                const float* __restrict__ aw,
                                                const float* __restrict__ ab,
                                                float* __restrict__ styles) {
  int gid = blockIdx.x*4 + (threadIdx.x >> 6);   // wave id 0..4095
  int lane = threadIdx.x & 63;
  int b = gid >> 9, i = gid & 511;
  const float* wr = w + b*512;
  const float* ar = aw + (size_t)i*512;
  float acc = 0.f;
  #pragma unroll
  for (int k = 0; k < 8; ++k) acc += wr[lane + 64*k]*ar[lane + 64*k];
  for (int off = 32; off; off >>= 1) acc += __shfl_down(acc, off);
  if (lane == 0) styles[gid] = acc*0.044194173824159216f + ab[i];  // 1/sqrt(512)
}

// ---------------------------------------------------------------- K2: s_n = styles * rsqrt(mean(styles^2))
__global__ __launch_bounds__(256) void k_snorm(const float* __restrict__ styles,
                                               float* __restrict__ s_n) {
  __shared__ float red[256];
  int tid = threadIdx.x;
  float acc = 0.f;
  for (int i = tid; i < 4096; i += 256) { float v = styles[i]; acc += v*v; }
  red[tid] = acc; __syncthreads();
  for (int s = 128; s > 0; s >>= 1) {
    if (tid < s) red[tid] += red[tid+s];
    __syncthreads();
  }
  float scale = 1.0f/sqrtf(red[0]*(1.0f/4096.0f));
  for (int i = tid; i < 4096; i += 256) s_n[i] = styles[i]*scale;
}

// ---------------------------------------------------------------- K3: g[O][I] = sum_tap wgt^2
__global__ __launch_bounds__(256) void k_g(const float* __restrict__ cw,
                                           float* __restrict__ g) {
  int id = blockIdx.x*256 + threadIdx.x;  // 0..262143
  if (id >= 512*512) return;
  const float* p = cw + (size_t)id*9;
  float acc = 0.f;
  #pragma unroll
  for (int t = 0; t < 9; ++t) acc += p[t]*p[t];
  g[id] = acc;
}

// ---------------------------------------------------------------- K4: scale_o[b][O] = wn[O]*demod[b][O]
__global__ __launch_bounds__(64) void k_scale(const float* __restrict__ g,
                                              const float* __restrict__ s_n,
                                              float* __restrict__ sco) {
  int blk = blockIdx.x;              // b*512 + O
  int b = blk >> 9, O = blk & 511;
  int lane = threadIdx.x;
  const float* gr = g + (size_t)O*512;
  const float* sr = s_n + b*512;
  float a1 = 0.f, a2 = 0.f;
  for (int I = lane; I < 512; I += 64) {
    float gg = gr[I], ss = sr[I];
    a1 += gg*ss*ss; a2 += gg;
  }
  for (int off = 32; off; off >>= 1) {
    a1 += __shfl_down(a1, off);
    a2 += __shfl_down(a2, off);
  }
  if (lane == 0) {
    float wn2 = 4608.f / a2;                              // 1/mean(wgt^2)
    sco[blk] = sqrtf(wn2) / sqrtf(wn2*a1 + 1e-8f);        // wn * rsqrt(sum wb^2 + eps)
  }
}

// ---------------------------------------------------------------- K5: Wp[O][tap][I] = f16(cw[O][I][tap])
__global__ __launch_bounds__(128) void k_wprep(const float* __restrict__ cw,
                                               f16* __restrict__ Wp) {
  int blk = blockIdx.x;              // O*9 + tap
  int O = blk / 9, t = blk - O*9;
  f16* op = Wp + ((size_t)O*9 + t)*512;
  const float* ip = cw + (size_t)O*512*9 + t;
  for (int I = threadIdx.x; I < 512; I += 128)
    op[I] = (f16)ip[(size_t)I*9];
}

// ---------------------------------------------------------------- K6: Xm[b][ih+2][iw+2][I] = f16(x[b][I][ih][iw]*s_n[b][I])
__global__ __launch_bounds__(256) void k_xmod(const float* __restrict__ x,
                                              const float* __restrict__ s_n,
                                              f16* __restrict__ Xm) {
  __shared__ float tile[128][65];
  int blk = blockIdx.x;              // b*256 + ih*4 + ic
  int ic = blk & 3, ih = (blk >> 2) & 63, b = blk >> 8;
  int I0 = ic*128;
  const float* xp = x + (((size_t)b*512 + I0)*64 + ih)*64;
  for (int idx = threadIdx.x; idx < 128*64; idx += 256) {
    int Il = idx >> 6, iw = idx & 63;
    tile[Il][iw] = xp[(size_t)Il*4096 + iw] * s_n[b*512 + I0 + Il];
  }
  __syncthreads();
  f16* op = Xm + (((size_t)b*PADH + ih + 2)*PADH + 2)*512 + I0;
  for (int idx = threadIdx.x; idx < 64*128; idx += 256) {
    int iw = idx >> 7, Il = idx & 127;
    op[(size_t)iw*512 + Il] = (f16)tile[Il][iw];
  }
}

// ---------------------------------------------------------------- K7: modulated conv as 9-tap implicit GEMM
// Tile: 128 O-rows x 256 positions. Grid flattened 1D (576 blocks):
//   b = gid&7  -> image pinned to one XCD (round-robin dispatch)
//   within XCD: pt fastest (A-tile L2-resident across 18 blocks), Ot outer,
//   boustrophedon pt order for B-tile reuse across Ot passes.
// 18 pt-tiles of 256; last tile overlaps (4100..4355) -> identical-value
// double stores, no clamps/guards anywhere.
__global__ __launch_bounds__(256, 2) void k_conv(const f16* __restrict__ Wp,
                                                 const f16* __restrict__ Xm,
                                                 const float* __restrict__ sco,
                                                 const float* __restrict__ bias,
                                                 f16* __restrict__ y1) {
  __shared__ f16x8 As[1024];   // 128 rows x 128B (16KB)
  __shared__ f16x8 Bs[2048];   // 256 rows x 128B (32KB)
  const int tid = threadIdx.x, lane = tid & 63, wave = tid >> 6;
  const int gid = blockIdx.x;
  const int b = gid & 7;
  const int r = gid >> 3;            // 0..71
  const int Oi = r / 18;
  int pi = r - Oi*18;                // 0..17
  if (Oi & 1) pi = 17 - pi;          // boustrophedon
  const int Ot = Oi * 128;
  const int pt0 = (pi < 17) ? pi*256 : 4100;

  // staging: wave stages A rows [wave*32,+32) (4 issues), B rows [wave*64,+64) (8 issues)
  const int srowA = wave*32 + (lane >> 3);
  const int srowB = wave*64 + (lane >> 3);
  const int cglob = (lane & 7) ^ (lane >> 3);     // global chunk feeding physical chunk lane&7
  const char* aP[4]; const char* bP[8];
  #pragma unroll
  for (int q = 0; q < 4; ++q)
    aP[q] = (const char*)Wp + (size_t)(Ot + srowA + q*8)*9216 + cglob*16;
  #pragma unroll
  for (int q = 0; q < 8; ++q) {
    int p = pt0 + srowB + q*8;                    // always <= 4355
    int oh = p/66, ow = p - oh*66;
    bP[q] = (const char*)Xm + (((size_t)b*PADH + oh)*PADH + ow)*1024 + cglob*16;
  }
  char* aL = (char*)As + wave*32*128;
  char* bL = (char*)Bs + wave*64*128;

  f32x4 acc[4][8] = {};
  const int wO = (wave & 1)*64, wPp = (wave >> 1)*128;
  const int m = lane & 15, quad = lane >> 4, mx = m & 7;

  for (int tap = 0; tap < 9; ++tap) {
    const int kh = tap/3, kw = tap - kh*3;
    const uint32_t bTap = (uint32_t)(kh*PADH + kw)*1024u;
    const uint32_t aTap = (uint32_t)tap*1024u;
    for (uint32_t I0b = 0; I0b < 1024; I0b += 128) {   // BK=64 f16
      __syncthreads();
      #pragma unroll
      for (int q = 0; q < 4; ++q) async16(aP[q] + aTap + I0b, aL + q*1024);
      #pragma unroll
      for (int q = 0; q < 8; ++q) async16(bP[q] + bTap + I0b, bL + q*1024);
      __syncthreads();
      #pragma unroll
      for (int ks = 0; ks < 2; ++ks) {
        f16x8 af[4], bf[8];
        #pragma unroll
        for (int i = 0; i < 4; ++i)
          af[i] = As[(wO + i*16 + m)*8 + ((ks*4 + quad) ^ mx)];
        #pragma unroll
        for (int j = 0; j < 8; ++j)
          bf[j] = Bs[(wPp + j*16 + m)*8 + ((ks*4 + quad) ^ mx)];
        #pragma unroll
        for (int i = 0; i < 4; ++i)
          #pragma unroll
          for (int j = 0; j < 8; ++j)
            acc[i][j] = __builtin_amdgcn_mfma_f32_16x16x32_f16(af[i], bf[j], acc[i][j], 0, 0, 0);
      }
    }
  }

  // epilogue: y1[b][O][p] = f16(acc*scale_o + bias); overlap tile double-writes identical values
  #pragma unroll
  for (int i = 0; i < 4; ++i) {
    #pragma unroll
    for (int rr = 0; rr < 4; ++rr) {
      int orow = Ot + wO + i*16 + quad*4 + rr;
      float sc = sco[b*COUT + orow];
      float bb = bias[orow];
      f16* yrow = y1 + ((size_t)(b*COUT + orow))*P_TOT;
      #pragma unroll
      for (int j = 0; j < 8; ++j) {
        int p = pt0 + wPp + j*16 + m;
        yrow[p] = (f16)(acc[i][j][rr]*sc + bb);
      }
    }
  }
}

// ---------------------------------------------------------------- K8: fused up-FIR -> lrelu/clamp -> down-FIR per channel
#define YPITCH 76
#define QPITCH 142
#define HPITCH 68
__global__ __launch_bounds__(256) void k_fir(const f16* __restrict__ y1,
                                             float* __restrict__ out,
                                             FirParams fp) {
  __shared__ float Yl[74*YPITCH];   // padded Y: rows/cols -4..69 (22496 B)
  __shared__ float VU[8*YPITCH];    // vertical-up chunk (2432 B)
  __shared__ float Qs[8*QPITCH];    // activated mid rows (4544 B)
  __shared__ float Hr[32*HPITCH];   // rolling horizontal-down rows (8704 B)
  const int tid = threadIdx.x;
  const f16* Y = y1 + (size_t)blockIdx.x * P_TOT;
  float* O = out + (size_t)blockIdx.x * (OUTS*OUTS);

  for (int i = tid; i < 74*YPITCH/2; i += 256)
    *(float2*)&Yl[2*i] = make_float2(0.f, 0.f);
  __syncthreads();
  const f16x2* Y2 = (const f16x2*)Y;
  for (int i = tid; i < 66*33; i += 256) {
    int r = i/33, d = i - 33*r;
    f16x2 v = Y2[33*r + d];
    *(float2*)&Yl[(r+4)*YPITCH + 4 + 2*d] = make_float2((float)v.x, (float)v.y);
  }
  __syncthreads();

  for (int k = 0; k <= 18; ++k) {
    const int m0 = 8*k;
    const int nr = (k < 17) ? 8 : (k == 17 ? 2 : 0);

    // ---- phase 1: vertical polyphase up (pairs share source rows) ----
    if (k < 18) {
      int npair = nr >> 1;
      if (tid < npair*37) {
        int tp = tid/37, c2 = tid - 37*tp;
        int T = (m0 >> 1) + tp;
        float e0=0.f,e1=0.f,o0=0.f,o1=0.f;
        #pragma unroll
        for (int a = 0; a < 6; ++a) {
          float2 v = *(const float2*)&Yl[(T+5-a)*YPITCH + 2*c2];
          e0 += fp.fu[2*a]*v.x;   e1 += fp.fu[2*a]*v.y;
          o0 += fp.fu[2*a+1]*v.x; o1 += fp.fu[2*a+1]*v.y;
        }
        *(float2*)&VU[(2*tp)*YPITCH   + 2*c2] = make_float2(e0, e1);
        *(float2*)&VU[(2*tp+1)*YPITCH + 2*c2] = make_float2(o0, o1);
      }
    }
    __syncthreads();

    // ---- phase 2: horizontal polyphase up + act ----
    if (k < 18) {
      if (tid < nr*23) {
        int lr = tid/23, ug = tid - 23*lr;
        int U0 = 3*ug;
        float r[8];
        #pragma unroll
        for (int d = 0; d < 8; ++d) r[d] = VU[lr*YPITCH + U0 + d];
        #pragma unroll
        for (int u = 0; u < 3; ++u) {
          float e=0.f, o=0.f;
          #pragma unroll
          for (int t = 0; t < 6; ++t) {
            float v = r[u+5-t];
            e += fp.fu[2*t]*v; o += fp.fu[2*t+1]*v;
          }
          e = (e >= 0.f ? e : 0.2f*e)*1.4142135623730951f;
          o = (o >= 0.f ? o : 0.2f*o)*1.4142135623730951f;
          e = fminf(fmaxf(e, -256.f), 256.f);
          o = fminf(fmaxf(o, -256.f), 256.f);
          *(float2*)&Qs[lr*QPITCH + 2*(U0+u)] = make_float2(e, o);
        }
      }
    }
    __syncthreads();

    // ---- phase 3: Hdown (waves 0-1) || delayed Vdown emit (waves 2-3) ----
    if (k < 18 && tid < 128) {
      int lr = tid >> 4, tg = tid & 15;
      if (lr < nr) {
        float q[18];
        #pragma unroll
        for (int d = 0; d < 18; ++d) q[d] = Qs[lr*QPITCH + 8*tg + d];
        float a0=0.f,a1=0.f,a2=0.f,a3=0.f;
        #pragma unroll
        for (int j = 0; j < 12; ++j) {
          float c = fp.fd[j];
          a0 += c*q[11-j]; a1 += c*q[13-j]; a2 += c*q[15-j]; a3 += c*q[17-j];
        }
        *(float4*)&Hr[((m0+lr)&31)*HPITCH + 4*tg] = make_float4(a0,a1,a2,a3);
      }
    }
    if (k >= 3 && tid >= 128) {
      int s = tid - 128;
      int pg = s >> 6, tc = s & 63;
      int tr0 = ((k-3) << 2) + 2*pg;
      int br = 2*tr0;
      float h[14];
      #pragma unroll
      for (int d = 0; d < 14; ++d) h[d] = Hr[((br+d)&31)*HPITCH + tc];
      float a0=0.f, a1=0.f;
      #pragma unroll
      for (int j = 0; j < 12; ++j) {
        float c = fp.fd[j];
        a0 += c*h[11-j]; a1 += c*h[13-j];
      }
      O[tr0*64 + tc]     = a0;
      O[(tr0+1)*64 + tc] = a1;
    }
    __syncthreads();
  }
}

// ---------------------------------------------------------------- host: Kaiser lowpass design (double precision)
static double bessel_i0(double x) {
  double t = 0.25*x*x, sum = 1.0, term = 1.0;
  for (int k = 1; k < 64; ++k) {
    term *= t/((double)k*(double)k);
    sum += term;
    if (term < 1e-18*sum) break;
  }
  return sum;
}

static void design_lp(int numtaps, double cutoff, double width, double fs, float* out) {
  const double PI = 3.14159265358979323846;
  double a = 2.285*(numtaps - 1)*PI*(width/(0.5*fs)) + 7.95;
  double beta;
  if (a > 50.0)      beta = 0.1102*(a - 8.7);
  else if (a > 21.0) beta = 0.5842*pow(a - 21.0, 0.4) + 0.07886*(a - 21.0);
  else               beta = 0.0;
  double c = cutoff/(fs*0.5);
  double alpha = (numtaps - 1)*0.5;
  double i0b = bessel_i0(beta);
  double h[16], s = 0.0;
  for (int n = 0; n < numtaps; ++n) {
    double mm = n - alpha;
    double x = c*mm;
    double snc = (x == 0.0) ? 1.0 : sin(PI*x)/(PI*x);
    double r = mm/alpha;
    double kais = bessel_i0(beta*sqrt(fmax(0.0, 1.0 - r*r)))/i0b;
    h[n] = c*snc*kais; s += h[n];
  }
  for (int n = 0; n < numtaps; ++n) out[n] = (float)(h[n]/s);
}

// ---------------------------------------------------------------- launcher
extern "C" void kernel_launch(void* const* d_in, const int* in_sizes, int n_in,
                              void* d_out, int out_size, void* d_ws, size_t ws_size,
                              hipStream_t stream) {
  const float* x  = (const float*)d_in[0];
  const float* w  = (const float*)d_in[1];
  const float* aw = (const float*)d_in[2];
  const float* ab = (const float*)d_in[3];
  const float* cw = (const float*)d_in[4];
  const float* cb = (const float*)d_in[5];
  float* out = (float*)d_out;

  char* ws = (char*)d_ws;
  size_t off = 0;
  auto alloc = [&](size_t bytes) -> char* {
    char* p = ws + off;
    off = (off + bytes + 255) & ~(size_t)255;
    return p;
  };
  float* styles = (float*)alloc(4096*4);
  float* s_n    = (float*)alloc(4096*4);
  float* g      = (float*)alloc((size_t)512*512*4);
  float* sco    = (float*)alloc(4096*4);
  f16*   Wp     = (f16*)alloc((size_t)512*9*512*2);
  const size_t XM_BYTES = (size_t)BATCH*PADH*PADH*512*2;
  f16*   Xm     = (f16*)alloc(XM_BYTES);
  f16*   y1     = (f16*)alloc((size_t)BATCH*COUT*P_TOT*2);
  (void)in_sizes; (void)n_in; (void)out_size; (void)ws_size;

  FirParams fp;
  design_lp(12, 32.0, 32.0, 128.0, fp.fu);
  design_lp(12, 32.0, 32.0, 128.0, fp.fd);
  for (int i = 0; i < 12; ++i) fp.fu[i] *= 2.0f;   // x2 per up stage = x4 total up gain (exact)

  hipMemsetAsync(Xm, 0, XM_BYTES, stream);   // zero padding halo
  hipLaunchKernelGGL(k_styles, dim3(1024),      dim3(256), 0, stream, w, aw, ab, styles);
  hipLaunchKernelGGL(k_snorm,  dim3(1),         dim3(256), 0, stream, styles, s_n);
  hipLaunchKernelGGL(k_g,      dim3(1024),      dim3(256), 0, stream, cw, g);
  hipLaunchKernelGGL(k_scale,  dim3(4096),      dim3(64),  0, stream, g, s_n, sco);
  hipLaunchKernelGGL(k_wprep,  dim3(4608),      dim3(128), 0, stream, cw, Wp);
  hipLaunchKernelGGL(k_xmod,   dim3(2048),      dim3(256), 0, stream, x, s_n, Xm);
  hipLaunchKernelGGL(k_conv,   dim3(576),       dim3(256), 0, stream, Wp, Xm, sco, cb, y1);
  hipLaunchKernelGGL(k_fir,    dim3(4096),      dim3(256), 0, stream, y1, out, fp);
}

// Round 4
// 488.072 us; speedup vs baseline: 1.8546x; 1.0197x over previous
//
#include <hip/hip_runtime.h>
#include <cmath>
#include <cstdint>
#include <cstddef>

typedef _Float16 f16;
typedef _Float16 f16x2 __attribute__((ext_vector_type(2)));
typedef _Float16 f16x8 __attribute__((ext_vector_type(8)));
typedef float f32x4 __attribute__((ext_vector_type(4)));

// ---- problem constants ----
#define BATCH 8
#define CIN   512
#define COUT  512
#define S0    64      // input spatial
#define S1    66      // conv output spatial (pad 2, k=3)
#define PADH  68      // padded input spatial for conv
#define P_TOT (S1*S1) // 4356 spatial positions per image
#define MID   138     // mid (upsampled+filtered) spatial
#define OUTS  64      // final output spatial

struct FirParams { float fu[12]; float fd[12]; };

// ---------------------------------------------------------------- helpers
__device__ __forceinline__ void async16(const char* g, char* l) {
  __builtin_amdgcn_global_load_lds((const __attribute__((address_space(1))) void*)g,
                                   (__attribute__((address_space(3))) void*)l, 16, 0, 0);
}

// ---------------------------------------------------------------- K1: styles = w @ (aw^T/sqrt(512)) + ab ; block-reduced sumsq atomic
__global__ __launch_bounds__(256) void k_styles(const float* __restrict__ w,
                                                const float* __restrict__ aw,
                                                const float* __restrict__ ab,
                                                float* __restrict__ styles,
                                                float* __restrict__ sumsq) {
  __shared__ float part[4];
  int wave = threadIdx.x >> 6, lane = threadIdx.x & 63;
  int gid = blockIdx.x*4 + wave;                 // 0..4095
  int b = gid >> 9, i = gid & 511;
  const float* wr = w + b*512;
  const float* ar = aw + (size_t)i*512;
  float acc = 0.f;
  #pragma unroll
  for (int k = 0; k < 8; ++k) acc += wr[lane + 64*k]*ar[lane + 64*k];
  for (int off = 32; off; off >>= 1) acc += __shfl_down(acc, off);
  if (lane == 0) {
    float v = acc*0.044194173824159216f + ab[i];  // 1/sqrt(512)
    styles[gid] = v;
    part[wave] = v*v;
  }
  __syncthreads();
  if (threadIdx.x == 0) atomicAdd(sumsq, part[0]+part[1]+part[2]+part[3]);
}

// ---------------------------------------------------------------- K2: fused wprep + g (one pass over cw)
__global__ __launch_bounds__(256) void k_wg(const float* __restrict__ cw,
                                            f16* __restrict__ Wp,
                                            float* __restrict__ g) {
  int O = blockIdx.x;
  const float* base = cw + (size_t)O*4608;
  for (int I = threadIdx.x; I < 512; I += 256) {
    float v[9]; float s = 0.f;
    #pragma unroll
    for (int t = 0; t < 9; ++t) { v[t] = base[I*9 + t]; s += v[t]*v[t]; }
    g[(size_t)O*512 + I] = s;
    #pragma unroll
    for (int t = 0; t < 9; ++t) Wp[((size_t)O*9 + t)*512 + I] = (f16)v[t];
  }
}

// ---------------------------------------------------------------- K3: scale_o[b][O] = wn[O]*demod[b][O]  (styles + sumsq form)
__global__ __launch_bounds__(64) void k_scale(const float* __restrict__ g,
                                              const float* __restrict__ styles,
                                              const float* __restrict__ sumsq,
                                              float* __restrict__ sco) {
  int blk = blockIdx.x;              // b*512 + O
  int b = blk >> 9, O = blk & 511;
  int lane = threadIdx.x;
  const float* gr = g + (size_t)O*512;
  const float* sr = styles + b*512;
  float a1 = 0.f, a2 = 0.f;
  for (int I = lane; I < 512; I += 64) {
    float gg = gr[I], ss = sr[I];
    a1 += gg*ss*ss; a2 += gg;
  }
  for (int off = 32; off; off >>= 1) {
    a1 += __shfl_down(a1, off);
    a2 += __shfl_down(a2, off);
  }
  if (lane == 0) {
    float kf = 4096.0f / (*sumsq);                        // rsqrt(mean styles^2)^2
    a1 *= kf;
    float wn2 = 4608.f / a2;                              // 1/mean(wgt^2)
    sco[blk] = sqrtf(wn2) / sqrtf(wn2*a1 + 1e-8f);        // wn * rsqrt(sum wb^2 + eps)
  }
}

// ---------------------------------------------------------------- K4: Xm[b][ih+2][iw+2][I] = f16(x*styles*scale)  (interior only)
__global__ __launch_bounds__(256) void k_xmod(const float* __restrict__ x,
                                              const float* __restrict__ styles,
                                              const float* __restrict__ sumsq,
                                              f16* __restrict__ Xm) {
  __shared__ float tile[128][65];
  int blk = blockIdx.x;              // b*256 + ih*4 + ic
  int ic = blk & 3, ih = (blk >> 2) & 63, b = blk >> 8;
  int I0 = ic*128;
  float sc = sqrtf(4096.0f / (*sumsq));
  const float* xp = x + (((size_t)b*512 + I0)*64 + ih)*64;
  for (int idx = threadIdx.x; idx < 128*64; idx += 256) {
    int Il = idx >> 6, iw = idx & 63;
    tile[Il][iw] = xp[(size_t)Il*4096 + iw] * (styles[b*512 + I0 + Il]*sc);
  }
  __syncthreads();
  f16* op = Xm + (((size_t)b*PADH + ih + 2)*PADH + 2)*512 + I0;
  for (int idx = threadIdx.x; idx < 64*128; idx += 256) {
    int iw = idx >> 7, Il = idx & 127;
    op[(size_t)iw*512 + Il] = (f16)tile[Il][iw];
  }
}

// ---------------------------------------------------------------- K5: zero Xm halo strips (replaces 76MB memset)
__global__ __launch_bounds__(256) void k_halo(f16* __restrict__ Xm) {
  int pix = blockIdx.x*4 + (threadIdx.x >> 6);   // 0..4223
  int lane = threadIdx.x & 63;
  int img = pix / 528, t = pix - img*528;
  int row, col;
  if (t < 272) { int rid = t/68; col = t - rid*68; row = (rid < 2) ? rid : 64 + rid; }
  else { int t2 = t - 272; int rid = t2 >> 2, cid = t2 & 3; row = rid + 2; col = (cid < 2) ? cid : 64 + cid; }
  float4* p = (float4*)(Xm + ((size_t)(img*PADH + row)*PADH + col)*512);
  p[lane] = make_float4(0.f, 0.f, 0.f, 0.f);
}

// ---------------------------------------------------------------- K6: modulated conv as 9-tap implicit GEMM
// 128 O x 128 p tiles, grid 1120 (4.4 blocks/CU for latency hiding).
// b = gid&7 pins image to XCD; within XCD pt fastest + boustrophedon for L2.
// 35 pt-tiles; last overlaps (4228..4355) -> guard-free duplicate stores.
__global__ __launch_bounds__(256) void k_conv(const f16* __restrict__ Wp,
                                              const f16* __restrict__ Xm,
                                              const float* __restrict__ sco,
                                              const float* __restrict__ bias,
                                              f16* __restrict__ y1) {
  __shared__ f16x8 As[1024];   // 128 rows x 128B (16KB)
  __shared__ f16x8 Bs[1024];
  const int tid = threadIdx.x, lane = tid & 63, wave = tid >> 6;
  const int gid = blockIdx.x;
  const int b = gid & 7;
  const int r = gid >> 3;            // 0..139
  const int Oi = r / 35;
  int pi = r - Oi*35;                // 0..34
  if (Oi & 1) pi = 34 - pi;          // boustrophedon
  const int Ot = Oi * 128;
  const int pt0 = (pi < 34) ? pi*128 : 4228;

  const int srow = wave*32 + (lane >> 3);
  const int cglob = (lane & 7) ^ (lane >> 3);     // global chunk feeding physical chunk lane&7
  const char* aP[4]; const char* bP[4];
  #pragma unroll
  for (int q = 0; q < 4; ++q) {
    aP[q] = (const char*)Wp + (size_t)(Ot + srow + q*8)*9216 + cglob*16;
    int p = pt0 + srow + q*8;                      // always <= 4355
    int oh = p/66, ow = p - oh*66;
    bP[q] = (const char*)Xm + (((size_t)b*PADH + oh)*PADH + ow)*1024 + cglob*16;
  }
  char* aL = (char*)As + wave*32*128;
  char* bL = (char*)Bs + wave*32*128;

  f32x4 acc[4][4] = {};
  const int wO = (wave & 1)*64, wPq = (wave >> 1)*64;
  const int m = lane & 15, quad = lane >> 4, mx = m & 7;

  for (int tap = 0; tap < 9; ++tap) {
    const int kh = tap/3, kw = tap - kh*3;
    const uint32_t bTap = (uint32_t)(kh*PADH + kw)*1024u;
    const uint32_t aTap = (uint32_t)tap*1024u;
    for (uint32_t I0b = 0; I0b < 1024; I0b += 128) {   // BK=64 f16
      __syncthreads();
      #pragma unroll
      for (int q = 0; q < 4; ++q) async16(aP[q] + aTap + I0b, aL + q*1024);
      #pragma unroll
      for (int q = 0; q < 4; ++q) async16(bP[q] + bTap + I0b, bL + q*1024);
      __syncthreads();
      #pragma unroll
      for (int ks = 0; ks < 2; ++ks) {
        f16x8 af[4], bf[4];
        #pragma unroll
        for (int i = 0; i < 4; ++i)
          af[i] = As[(wO + i*16 + m)*8 + ((ks*4 + quad) ^ mx)];
        #pragma unroll
        for (int j = 0; j < 4; ++j)
          bf[j] = Bs[(wPq + j*16 + m)*8 + ((ks*4 + quad) ^ mx)];
        #pragma unroll
        for (int i = 0; i < 4; ++i)
          #pragma unroll
          for (int j = 0; j < 4; ++j)
            acc[i][j] = __builtin_amdgcn_mfma_f32_16x16x32_f16(af[i], bf[j], acc[i][j], 0, 0, 0);
      }
    }
  }

  // epilogue: y1[b][O][p] = f16(acc*scale_o + bias); overlap tile double-writes identical values
  #pragma unroll
  for (int i = 0; i < 4; ++i) {
    #pragma unroll
    for (int rr = 0; rr < 4; ++rr) {
      int orow = Ot + wO + i*16 + quad*4 + rr;
      float sc = sco[b*COUT + orow];
      float bb = bias[orow];
      f16* yrow = y1 + ((size_t)(b*COUT + orow))*P_TOT;
      #pragma unroll
      for (int j = 0; j < 4; ++j) {
        int p = pt0 + wPq + j*16 + m;
        yrow[p] = (f16)(acc[i][j][rr]*sc + bb);
      }
    }
  }
}

// ---------------------------------------------------------------- K7: fused up-FIR -> lrelu/clamp -> down-FIR per channel
// v3: chunk=16 mid rows, 4 full-occupancy phases, 36 barriers total,
// Vdown lag-1 with 32-row rolling H (barrier-separated, race-free).
#define YPITCH 76
#define QPITCH 142
#define HPITCH 68
__global__ __launch_bounds__(256) void k_fir(const f16* __restrict__ y1,
                                             float* __restrict__ out,
                                             FirParams fp) {
  __shared__ float Yl[74*YPITCH];   // padded Y rows/cols -4..69 (22496 B)
  __shared__ float VU[16*YPITCH];   // vertical-up chunk (4864 B)
  __shared__ float Qs[16*QPITCH];   // activated mid rows (9088 B)
  __shared__ float Hr[32*HPITCH];   // rolling horizontal-down rows (8704 B)  total 45152 B
  const int tid = threadIdx.x;
  const f16* Y = y1 + (size_t)blockIdx.x * P_TOT;
  float* O = out + (size_t)blockIdx.x * (OUTS*OUTS);

  // stage Y into padded LDS (zero halo, then vectorized f16x2 load)
  for (int i = tid; i < 74*YPITCH/2; i += 256)
    *(float2*)&Yl[2*i] = make_float2(0.f, 0.f);
  __syncthreads();
  const f16x2* Y2 = (const f16x2*)Y;
  for (int i = tid; i < 66*33; i += 256) {
    int r = i/33, d = i - 33*r;
    f16x2 v = Y2[33*r + d];
    *(float2*)&Yl[(r+4)*YPITCH + 4 + 2*d] = make_float2((float)v.x, (float)v.y);
  }
  __syncthreads();

  for (int k = 0; k < 9; ++k) {
    const int m0 = 16*k;
    const int nr = (k < 8) ? 16 : 10;
    const int npair = nr >> 1;

    // ---- P1: vertical polyphase up (pairs share 6 source rows) ----
    for (int it = tid; it < npair*37; it += 256) {
      int p = it/37, c2 = it - 37*p;
      int T = 8*k + p;                 // mid rows 2T,2T+1
      float e0=0.f,e1=0.f,o0=0.f,o1=0.f;
      #pragma unroll
      for (int a = 0; a < 6; ++a) {
        float2 v = *(const float2*)&Yl[(T+5-a)*YPITCH + 2*c2];
        e0 += fp.fu[2*a]*v.x;   e1 += fp.fu[2*a]*v.y;
        o0 += fp.fu[2*a+1]*v.x; o1 += fp.fu[2*a+1]*v.y;
      }
      *(float2*)&VU[(2*p)*YPITCH   + 2*c2] = make_float2(e0, e1);
      *(float2*)&VU[(2*p+1)*YPITCH + 2*c2] = make_float2(o0, o1);
    }
    __syncthreads();

    // ---- P2: horizontal polyphase up + act (3 col-pairs/item, 8 shared reads) ----
    for (int it = tid; it < nr*23; it += 256) {
      int lr = it/23, ug = it - 23*lr;
      int U0 = 3*ug;
      float rv[8];
      #pragma unroll
      for (int d = 0; d < 8; ++d) rv[d] = VU[lr*YPITCH + U0 + d];
      #pragma unroll
      for (int u = 0; u < 3; ++u) {
        float e=0.f, o=0.f;
        #pragma unroll
        for (int t = 0; t < 6; ++t) {
          float v = rv[u+5-t];
          e += fp.fu[2*t]*v; o += fp.fu[2*t+1]*v;
        }
        e = (e >= 0.f ? e : 0.2f*e)*1.4142135623730951f;
        o = (o >= 0.f ? o : 0.2f*o)*1.4142135623730951f;
        e = fminf(fmaxf(e, -256.f), 256.f);
        o = fminf(fmaxf(o, -256.f), 256.f);
        *(float2*)&Qs[lr*QPITCH + 2*(U0+u)] = make_float2(e, o);
      }
    }
    __syncthreads();

    // ---- P3a: horizontal down (exact 256-thread fit at nr=16) ----
    if (tid < nr*16) {
      int lr = tid >> 4, tg = tid & 15;
      float q[18];
      #pragma unroll
      for (int d = 0; d < 18; ++d) q[d] = Qs[lr*QPITCH + 8*tg + d];
      float a0=0.f,a1=0.f,a2=0.f,a3=0.f;
      #pragma unroll
      for (int j = 0; j < 12; ++j) {
        float c = fp.fd[j];
        a0 += c*q[11-j]; a1 += c*q[13-j]; a2 += c*q[15-j]; a3 += c*q[17-j];
      }
      *(float4*)&Hr[((m0+lr)&31)*HPITCH + 4*tg] = make_float4(a0,a1,a2,a3);
    }
    __syncthreads();

    // ---- P3b: vertical down emit, lag 1 chunk (rows 8(k-1)..8k-1) ----
    if (k >= 1) {
      #pragma unroll
      for (int h = 0; h < 2; ++h) {
        int s = tid + 256*h;
        int tr = 8*(k-1) + (s >> 6), tc = s & 63;
        float acc = 0.f;
        #pragma unroll
        for (int j = 0; j < 12; ++j)
          acc += fp.fd[j]*Hr[((2*tr + 11 - j)&31)*HPITCH + tc];
        O[tr*64 + tc] = acc;
      }
    }
    __syncthreads();   // separates P3b reads from next chunk's P3a writes (slot aliasing)
  }
}

// ---------------------------------------------------------------- host: Kaiser lowpass design (double precision)
static double bessel_i0(double x) {
  double t = 0.25*x*x, sum = 1.0, term = 1.0;
  for (int k = 1; k < 64; ++k) {
    term *= t/((double)k*(double)k);
    sum += term;
    if (term < 1e-18*sum) break;
  }
  return sum;
}

static void design_lp(int numtaps, double cutoff, double width, double fs, float* out) {
  const double PI = 3.14159265358979323846;
  double a = 2.285*(numtaps - 1)*PI*(width/(0.5*fs)) + 7.95;
  double beta;
  if (a > 50.0)      beta = 0.1102*(a - 8.7);
  else if (a > 21.0) beta = 0.5842*pow(a - 21.0, 0.4) + 0.07886*(a - 21.0);
  else               beta = 0.0;
  double c = cutoff/(fs*0.5);
  double alpha = (numtaps - 1)*0.5;
  double i0b = bessel_i0(beta);
  double h[16], s = 0.0;
  for (int n = 0; n < numtaps; ++n) {
    double mm = n - alpha;
    double x = c*mm;
    double snc = (x == 0.0) ? 1.0 : sin(PI*x)/(PI*x);
    double r = mm/alpha;
    double kais = bessel_i0(beta*sqrt(fmax(0.0, 1.0 - r*r)))/i0b;
    h[n] = c*snc*kais; s += h[n];
  }
  for (int n = 0; n < numtaps; ++n) out[n] = (float)(h[n]/s);
}

// ---------------------------------------------------------------- launcher
extern "C" void kernel_launch(void* const* d_in, const int* in_sizes, int n_in,
                              void* d_out, int out_size, void* d_ws, size_t ws_size,
                              hipStream_t stream) {
  const float* x  = (const float*)d_in[0];
  const float* w  = (const float*)d_in[1];
  const float* aw = (const float*)d_in[2];
  const float* ab = (const float*)d_in[3];
  const float* cw = (const float*)d_in[4];
  const float* cb = (const float*)d_in[5];
  float* out = (float*)d_out;

  char* ws = (char*)d_ws;
  size_t off = 0;
  auto alloc = [&](size_t bytes) -> char* {
    char* p = ws + off;
    off = (off + bytes + 255) & ~(size_t)255;
    return p;
  };
  float* styles = (float*)alloc(4096*4);
  float* g      = (float*)alloc((size_t)512*512*4);
  float* sco    = (float*)alloc(4096*4);
  f16*   Wp     = (f16*)alloc((size_t)512*9*512*2);
  f16*   Xm     = (f16*)alloc((size_t)BATCH*PADH*PADH*512*2);
  f16*   y1     = (f16*)alloc((size_t)BATCH*COUT*P_TOT*2);
  float* sumsq  = (float*)alloc(4);
  (void)in_sizes; (void)n_in; (void)out_size; (void)ws_size;

  FirParams fp;
  design_lp(12, 32.0, 32.0, 128.0, fp.fu);
  design_lp(12, 32.0, 32.0, 128.0, fp.fd);
  for (int i = 0; i < 12; ++i) fp.fu[i] *= 2.0f;   // x2 per up stage = x4 total up gain (exact)

  hipMemsetAsync(sumsq, 0, 4, stream);
  hipLaunchKernelGGL(k_styles, dim3(1024), dim3(256), 0, stream, w, aw, ab, styles, sumsq);
  hipLaunchKernelGGL(k_wg,     dim3(512),  dim3(256), 0, stream, cw, Wp, g);
  hipLaunchKernelGGL(k_scale,  dim3(4096), dim3(64),  0, stream, g, styles, sumsq, sco);
  hipLaunchKernelGGL(k_xmod,   dim3(2048), dim3(256), 0, stream, x, styles, sumsq, Xm);
  hipLaunchKernelGGL(k_halo,   dim3(1056), dim3(256), 0, stream, Xm);
  hipLaunchKernelGGL(k_conv,   dim3(1120), dim3(256), 0, stream, Wp, Xm, sco, cb, y1);
  hipLaunchKernelGGL(k_fir,    dim3(4096), dim3(256), 0, stream, y1, out, fp);
}